// Round 2
// baseline (952.723 us; speedup 1.0000x reference)
//
#include <hip/hip_runtime.h>
#include <cstdint>
#include <cstddef>

#define DEV __device__ __forceinline__

typedef __attribute__((ext_vector_type(8))) __bf16 bf16x8;
typedef __attribute__((ext_vector_type(4))) float f32x4;
typedef __attribute__((ext_vector_type(4))) uint32_t u32x4;

// Problem constants
constexpr int BB = 2, SS = 2048, DMOD = 1024, HH = 16, DDEP = 64;
constexpr int MM = BB * SS;          // 4096 rows for the projection GEMMs
constexpr float SCL = 0.125f;        // 1/sqrt(64)

// Workspace layout (bytes). Peak usage 56 MB via aliasing:
//  qb/kb/vb are dead after the QKV projections; VhT and ctx alias over them.
constexpr size_t SZ_ACT = (size_t)MM * DMOD * 2;   // bf16 [4096][1024] = 8 MB
constexpr size_t SZ_W = (size_t)DMOD * DMOD * 2;   // bf16 [1024][1024] = 2 MB
constexpr size_t OFF_QB = 0;
constexpr size_t OFF_KB = OFF_QB + SZ_ACT;
constexpr size_t OFF_VB = OFF_KB + SZ_ACT;
constexpr size_t OFF_WQT = OFF_VB + SZ_ACT;
constexpr size_t OFF_WKT = OFF_WQT + SZ_W;
constexpr size_t OFF_WVT = OFF_WKT + SZ_W;
constexpr size_t OFF_WOT = OFF_WVT + SZ_W;
constexpr size_t OFF_QH = OFF_WOT + SZ_W;
constexpr size_t OFF_KH = OFF_QH + SZ_ACT;
constexpr size_t OFF_VH = OFF_KH + SZ_ACT;
constexpr size_t OFF_VHT = OFF_QB;                 // alias (VhT: 32*64*2048*2 = 8 MB)
constexpr size_t OFF_CTX = OFF_KB;                 // alias (ctx: 8 MB)
// total = OFF_VH + SZ_ACT = 56 MB

DEV uint16_t f2bf(float f) {
  uint32_t u = __builtin_bit_cast(uint32_t, f);
  u += 0x7fffu + ((u >> 16) & 1u);   // RNE
  return (uint16_t)(u >> 16);
}
DEV uint32_t pk2(float a, float b) { return (uint32_t)f2bf(a) | ((uint32_t)f2bf(b) << 16); }
DEV f32x4 mfma16(bf16x8 a, bf16x8 b, f32x4 c) {
  return __builtin_amdgcn_mfma_f32_16x16x32_bf16(a, b, c, 0, 0, 0);
}

// ---------------------------------------------------------------- cast fp32 -> bf16 (8 elems/thread)
__global__ __launch_bounds__(256) void cast_bf16(const float4* __restrict__ in, u32x4* __restrict__ out) {
  size_t i = (size_t)blockIdx.x * 256 + threadIdx.x;
  float4 a = in[i * 2], b = in[i * 2 + 1];
  u32x4 o;
  o.x = pk2(a.x, a.y); o.y = pk2(a.z, a.w);
  o.z = pk2(b.x, b.y); o.w = pk2(b.z, b.w);
  out[i] = o;
}

// ---------------------------------------------------------------- W [K][N] fp32 -> W^T [N][K] bf16
__global__ __launch_bounds__(256) void wtrans(const float* __restrict__ W, uint16_t* __restrict__ WT) {
  __shared__ uint16_t tile[64 * 72];
  const int kb = blockIdx.x * 64, nb = blockIdx.y * 64;
  const int t = threadIdx.x;
  {
    const int kl = t >> 2, nc = (t & 3) * 16;
    const float4* src = reinterpret_cast<const float4*>(&W[(size_t)(kb + kl) * DMOD + nb + nc]);
    float4 v0 = src[0], v1 = src[1], v2 = src[2], v3 = src[3];
    uint16_t* d = &tile[kl * 72 + nc];
    d[0] = f2bf(v0.x); d[1] = f2bf(v0.y); d[2] = f2bf(v0.z); d[3] = f2bf(v0.w);
    d[4] = f2bf(v1.x); d[5] = f2bf(v1.y); d[6] = f2bf(v1.z); d[7] = f2bf(v1.w);
    d[8] = f2bf(v2.x); d[9] = f2bf(v2.y); d[10] = f2bf(v2.z); d[11] = f2bf(v2.w);
    d[12] = f2bf(v3.x); d[13] = f2bf(v3.y); d[14] = f2bf(v3.z); d[15] = f2bf(v3.w);
  }
  __syncthreads();
  {
    const int n = t >> 2, kc = (t & 3) * 16;
    uint16_t r[16];
#pragma unroll
    for (int j = 0; j < 16; ++j) r[j] = tile[(kc + j) * 72 + n];
    u32x4 o0, o1;
    o0.x = r[0] | ((uint32_t)r[1] << 16);  o0.y = r[2] | ((uint32_t)r[3] << 16);
    o0.z = r[4] | ((uint32_t)r[5] << 16);  o0.w = r[6] | ((uint32_t)r[7] << 16);
    o1.x = r[8] | ((uint32_t)r[9] << 16);  o1.y = r[10] | ((uint32_t)r[11] << 16);
    o1.z = r[12] | ((uint32_t)r[13] << 16); o1.w = r[14] | ((uint32_t)r[15] << 16);
    uint16_t* dst = &WT[(size_t)(nb + n) * DMOD + kb + kc];
    *reinterpret_cast<u32x4*>(dst) = o0;
    *reinterpret_cast<u32x4*>(dst + 8) = o1;
  }
}

// ---------------------------------------------------------------- Vh [B,S,H,D] -> VhT [B*H, D, S] (bf16)
__global__ __launch_bounds__(256) void vtrans(const uint16_t* __restrict__ Vh, uint16_t* __restrict__ VhT) {
  __shared__ uint16_t tile[64 * 72];
  const int sb = blockIdx.x * 64;   // s tile
  const int bh = blockIdx.y;        // 0..31
  const int b = bh >> 4, h = bh & 15;
  const int t = threadIdx.x;
  {
    const int sl = t >> 2, dc = (t & 3) * 16;
    const u32x4* src = reinterpret_cast<const u32x4*>(&Vh[(size_t)(b * SS + sb + sl) * DMOD + h * DDEP + dc]);
    *reinterpret_cast<u32x4*>(&tile[sl * 72 + dc]) = src[0];
    *reinterpret_cast<u32x4*>(&tile[sl * 72 + dc + 8]) = src[1];
  }
  __syncthreads();
  {
    const int d = t >> 2, sc = (t & 3) * 16;
    uint16_t r[16];
#pragma unroll
    for (int j = 0; j < 16; ++j) r[j] = tile[(sc + j) * 72 + d];
    u32x4 o0, o1;
    o0.x = r[0] | ((uint32_t)r[1] << 16);  o0.y = r[2] | ((uint32_t)r[3] << 16);
    o0.z = r[4] | ((uint32_t)r[5] << 16);  o0.w = r[6] | ((uint32_t)r[7] << 16);
    o1.x = r[8] | ((uint32_t)r[9] << 16);  o1.y = r[10] | ((uint32_t)r[11] << 16);
    o1.z = r[12] | ((uint32_t)r[13] << 16); o1.w = r[14] | ((uint32_t)r[15] << 16);
    uint16_t* dst = &VhT[((size_t)bh * DDEP + d) * SS + sb + sc];
    *reinterpret_cast<u32x4*>(dst) = o0;
    *reinterpret_cast<u32x4*>(dst + 8) = o1;
  }
}

// ---------------------------------------------------------------- C = A @ B^T + bias; A,Bt bf16; out bf16 or f32
template <int OUTF32>
__global__ __launch_bounds__(256) void gemm_bt(
    const uint16_t* __restrict__ A, const uint16_t* __restrict__ Bt,
    const float* __restrict__ bias, void* __restrict__ Cout,
    int Md, int Nd, int Kd) {
  __shared__ uint16_t As[128 * 64];
  __shared__ uint16_t Bs[128 * 64];
  const int t = threadIdx.x;
  const int lane = t & 63, w = t >> 6;
  const int wr = w >> 1, wc = w & 1;
  const int g = lane >> 4, r16 = lane & 15;
  const int ntiles = Nd >> 7;
  const int mt = blockIdx.x / ntiles, nt = blockIdx.x % ntiles;
  char* AsB = reinterpret_cast<char*>(As);
  char* BsB = reinterpret_cast<char*>(Bs);

  f32x4 acc[4][4] = {};
  const int nkt = Kd >> 6;
  for (int kt = 0; kt < nkt; ++kt) {
#pragma unroll
    for (int i = 0; i < 4; ++i) {
      int idx = i * 256 + t;
      int row = idx >> 3, ch = idx & 7;
      int sw = row * 128 + ((ch * 16) ^ ((row & 7) << 4));   // XOR swizzle, 16B slots
      *reinterpret_cast<u32x4*>(AsB + sw) =
          *reinterpret_cast<const u32x4*>(A + (size_t)(mt * 128 + row) * Kd + kt * 64 + ch * 8);
      *reinterpret_cast<u32x4*>(BsB + sw) =
          *reinterpret_cast<const u32x4*>(Bt + (size_t)(nt * 128 + row) * Kd + kt * 64 + ch * 8);
    }
    __syncthreads();
#pragma unroll
    for (int kk = 0; kk < 2; ++kk) {
      bf16x8 af[4], bfr[4];
#pragma unroll
      for (int mf = 0; mf < 4; ++mf) {
        int row = wr * 64 + mf * 16 + r16;
        af[mf] = *reinterpret_cast<const bf16x8*>(AsB + row * 128 + ((kk * 64 + g * 16) ^ ((row & 7) << 4)));
      }
#pragma unroll
      for (int nf = 0; nf < 4; ++nf) {
        int row = wc * 64 + nf * 16 + r16;
        bfr[nf] = *reinterpret_cast<const bf16x8*>(BsB + row * 128 + ((kk * 64 + g * 16) ^ ((row & 7) << 4)));
      }
#pragma unroll
      for (int mf = 0; mf < 4; ++mf)
#pragma unroll
        for (int nf = 0; nf < 4; ++nf)
          acc[mf][nf] = mfma16(af[mf], bfr[nf], acc[mf][nf]);
    }
    __syncthreads();
  }
  float bv[4];
#pragma unroll
  for (int nf = 0; nf < 4; ++nf) bv[nf] = bias[nt * 128 + wc * 64 + nf * 16 + r16];
#pragma unroll
  for (int mf = 0; mf < 4; ++mf)
#pragma unroll
    for (int nf = 0; nf < 4; ++nf)
#pragma unroll
      for (int r = 0; r < 4; ++r) {
        int row = mt * 128 + wr * 64 + mf * 16 + g * 4 + r;
        int col = nt * 128 + wc * 64 + nf * 16 + r16;
        float v0 = acc[mf][nf][r] + bv[nf];
        if (OUTF32)
          reinterpret_cast<float*>(Cout)[(size_t)row * Nd + col] = v0;
        else
          reinterpret_cast<uint16_t*>(Cout)[(size_t)row * Nd + col] = f2bf(v0);
      }
}

// ---------------------------------------------------------------- fused scores+softmax+attn-write+PV
// grid: 512 blocks = (b,h) x 16 q-tiles of 128 rows; 4 waves x 32 q-rows each.
// Two-pass: pass 1 = online (m,l) only (no HBM score traffic); pass 2 =
// recompute scores (QK^T MFMA is cheap: 17 GF total), write normalized attn
// (the mandatory 537 MB output), accumulate PV from a per-wave LDS P tile.
__global__ __launch_bounds__(256) void attn_fused(
    const uint16_t* __restrict__ Qh, const uint16_t* __restrict__ Kh,
    const uint16_t* __restrict__ VhT, const float* __restrict__ mask,
    float* __restrict__ attn, uint16_t* __restrict__ ctx) {
  __shared__ uint16_t Plds[4 * 32 * 128];  // per-wave [32][128] bf16, XOR-swizzled
  const int t = threadIdx.x;
  const int lane = t & 63, w = t >> 6;
  const int g = lane >> 4, c16 = lane & 15;
  const int bid = blockIdx.x;
  const int bh = bid >> 4, qt = bid & 15;
  const int b = bh >> 4, h = bh & 15;

  const uint16_t* Qbase = Qh + ((size_t)(b * SS + qt * 128 + w * 32)) * DMOD + h * DDEP;
  const uint16_t* Kbase = Kh + ((size_t)b * SS) * DMOD + h * DDEP;
  const uint16_t* Vbase = VhT + (size_t)bh * DDEP * SS;
  const float* mbase = mask + (size_t)b * SS;
  char* Pw = reinterpret_cast<char*>(Plds) + w * (32 * 256);

  // Q fragments held in registers for the whole kernel
  bf16x8 qf[2][2];
#pragma unroll
  for (int rf = 0; rf < 2; ++rf)
#pragma unroll
    for (int kk = 0; kk < 2; ++kk)
      qf[rf][kk] = *reinterpret_cast<const bf16x8*>(Qbase + (size_t)(rf * 16 + c16) * DMOD + kk * 32 + g * 8);

  float m_[2][4], l_[2][4];
#pragma unroll
  for (int rf = 0; rf < 2; ++rf)
#pragma unroll
    for (int r = 0; r < 4; ++r) { m_[rf][r] = -3.0e38f; l_[rf][r] = 0.f; }

  // ---- pass 1: online (m, l) over all 16 key-tiles
  for (int kt = 0; kt < 16; ++kt) {
    f32x4 sacc[2][8] = {};
#pragma unroll
    for (int nf = 0; nf < 8; ++nf) {
      const uint16_t* kp = Kbase + (size_t)(kt * 128 + nf * 16 + c16) * DMOD + g * 8;
      bf16x8 b0 = *reinterpret_cast<const bf16x8*>(kp);
      bf16x8 b1 = *reinterpret_cast<const bf16x8*>(kp + 32);
      sacc[0][nf] = mfma16(qf[0][0], b0, sacc[0][nf]);
      sacc[0][nf] = mfma16(qf[0][1], b1, sacc[0][nf]);
      sacc[1][nf] = mfma16(qf[1][0], b0, sacc[1][nf]);
      sacc[1][nf] = mfma16(qf[1][1], b1, sacc[1][nf]);
    }
    float mv[8];
#pragma unroll
    for (int nf = 0; nf < 8; ++nf) mv[nf] = mbase[kt * 128 + nf * 16 + c16] * -1e9f;
#pragma unroll
    for (int rf = 0; rf < 2; ++rf) {
#pragma unroll
      for (int r = 0; r < 4; ++r) {
        float tm = -3.0e38f;
#pragma unroll
        for (int nf = 0; nf < 8; ++nf) {
          float sv = sacc[rf][nf][r] * SCL + mv[nf];
          sacc[rf][nf][r] = sv;
          tm = fmaxf(tm, sv);
        }
#pragma unroll
        for (int d = 1; d < 16; d <<= 1) tm = fmaxf(tm, __shfl_xor(tm, d));
        float mo = m_[rf][r];
        float mn = fmaxf(mo, tm);
        float sum = 0.f;
#pragma unroll
        for (int nf = 0; nf < 8; ++nf) sum += __expf(sacc[rf][nf][r] - mn);
#pragma unroll
        for (int d = 1; d < 16; d <<= 1) sum += __shfl_xor(sum, d);
        l_[rf][r] = l_[rf][r] * __expf(mo - mn) + sum;
        m_[rf][r] = mn;
      }
    }
  }
  float li[2][4];
#pragma unroll
  for (int rf = 0; rf < 2; ++rf)
#pragma unroll
    for (int r = 0; r < 4; ++r) li[rf][r] = 1.f / l_[rf][r];

  // ---- pass 2: recompute scores, write normalized attn, accumulate PV
  f32x4 cacc[2][4] = {};
  float* abase = attn + ((size_t)bh * SS + qt * 128 + w * 32) * SS;

  for (int kt = 0; kt < 16; ++kt) {
    f32x4 sacc[2][8] = {};
#pragma unroll
    for (int nf = 0; nf < 8; ++nf) {
      const uint16_t* kp = Kbase + (size_t)(kt * 128 + nf * 16 + c16) * DMOD + g * 8;
      bf16x8 b0 = *reinterpret_cast<const bf16x8*>(kp);
      bf16x8 b1 = *reinterpret_cast<const bf16x8*>(kp + 32);
      sacc[0][nf] = mfma16(qf[0][0], b0, sacc[0][nf]);
      sacc[0][nf] = mfma16(qf[0][1], b1, sacc[0][nf]);
      sacc[1][nf] = mfma16(qf[1][0], b0, sacc[1][nf]);
      sacc[1][nf] = mfma16(qf[1][1], b1, sacc[1][nf]);
    }
    float mv[8];
#pragma unroll
    for (int nf = 0; nf < 8; ++nf) mv[nf] = mbase[kt * 128 + nf * 16 + c16] * -1e9f;
#pragma unroll
    for (int rf = 0; rf < 2; ++rf)
#pragma unroll
      for (int nf = 0; nf < 8; ++nf)
#pragma unroll
        for (int r = 0; r < 4; ++r) {
          int prow = rf * 16 + g * 4 + r;
          float p = __expf(sacc[rf][nf][r] * SCL + mv[nf] - m_[rf][r]) * li[rf][r];
          abase[(size_t)prow * SS + kt * 128 + nf * 16 + c16] = p;
          *reinterpret_cast<uint16_t*>(
              Pw + prow * 256 + (((nf * 16 + c16) * 2) ^ ((prow & 7) << 4))) = f2bf(p);
        }
    // PV: ctx += P(32x128) @ V(128x64); per-wave LDS, intra-wave dep (no barrier needed)
#pragma unroll
    for (int kk = 0; kk < 4; ++kk) {
      bf16x8 pa[2];
#pragma unroll
      for (int rf = 0; rf < 2; ++rf) {
        int arow = rf * 16 + c16;
        pa[rf] = *reinterpret_cast<const bf16x8*>(
            Pw + arow * 256 + ((kk * 64 + g * 16) ^ ((arow & 7) << 4)));
      }
#pragma unroll
      for (int nf = 0; nf < 4; ++nf) {
        bf16x8 vf = *reinterpret_cast<const bf16x8*>(
            Vbase + (size_t)(nf * 16 + c16) * SS + kt * 128 + kk * 32 + g * 8);
        cacc[0][nf] = mfma16(pa[0], vf, cacc[0][nf]);
        cacc[1][nf] = mfma16(pa[1], vf, cacc[1][nf]);
      }
    }
  }
  // ctx write: [B,S,H*D] bf16 (feeds the output projection directly)
#pragma unroll
  for (int rf = 0; rf < 2; ++rf)
#pragma unroll
    for (int nf = 0; nf < 4; ++nf)
#pragma unroll
      for (int r = 0; r < 4; ++r) {
        int row = qt * 128 + w * 32 + rf * 16 + g * 4 + r;
        ctx[((size_t)(b * SS + row)) * DMOD + h * DDEP + nf * 16 + c16] = f2bf(cacc[rf][nf][r]);
      }
}

// ----------------------------------------------------------------
extern "C" void kernel_launch(void* const* d_in, const int* in_sizes, int n_in,
                              void* d_out, int out_size, void* d_ws, size_t ws_size,
                              hipStream_t stream) {
  (void)in_sizes; (void)n_in; (void)out_size; (void)ws_size;
  const float* q = (const float*)d_in[0];
  const float* k = (const float*)d_in[1];
  const float* v = (const float*)d_in[2];
  const float* mask = (const float*)d_in[3];
  const float* wq = (const float*)d_in[4];
  const float* bq = (const float*)d_in[5];
  const float* wk = (const float*)d_in[6];
  const float* bk = (const float*)d_in[7];
  const float* wv = (const float*)d_in[8];
  const float* bvv = (const float*)d_in[9];
  const float* wo = (const float*)d_in[10];
  const float* bo = (const float*)d_in[11];

  char* ws = (char*)d_ws;
  uint16_t* qb = (uint16_t*)(ws + OFF_QB);
  uint16_t* kb = (uint16_t*)(ws + OFF_KB);
  uint16_t* vb = (uint16_t*)(ws + OFF_VB);
  uint16_t* wqT = (uint16_t*)(ws + OFF_WQT);
  uint16_t* wkT = (uint16_t*)(ws + OFF_WKT);
  uint16_t* wvT = (uint16_t*)(ws + OFF_WVT);
  uint16_t* woT = (uint16_t*)(ws + OFF_WOT);
  uint16_t* Qhp = (uint16_t*)(ws + OFF_QH);
  uint16_t* Khp = (uint16_t*)(ws + OFF_KH);
  uint16_t* Vhp = (uint16_t*)(ws + OFF_VH);
  uint16_t* VhTp = (uint16_t*)(ws + OFF_VHT);   // aliases qb (dead after gemm #1)
  uint16_t* ctxp = (uint16_t*)(ws + OFF_CTX);   // aliases kb (dead after gemm #2)

  float* outp = (float*)d_out;
  float* attnp = outp + (size_t)MM * DMOD;

  // 1) casts: 4,194,304 elems each / 8 per thread = 524288 threads
  cast_bf16<<<2048, 256, 0, stream>>>((const float4*)q, (u32x4*)qb);
  cast_bf16<<<2048, 256, 0, stream>>>((const float4*)k, (u32x4*)kb);
  cast_bf16<<<2048, 256, 0, stream>>>((const float4*)v, (u32x4*)vb);
  // 2) weight transpose-casts
  wtrans<<<dim3(16, 16), 256, 0, stream>>>(wq, wqT);
  wtrans<<<dim3(16, 16), 256, 0, stream>>>(wk, wkT);
  wtrans<<<dim3(16, 16), 256, 0, stream>>>(wv, wvT);
  wtrans<<<dim3(16, 16), 256, 0, stream>>>(wo, woT);
  // 3) QKV projections: [4096,1024] = [4096,1024] @ [1024,1024]^T + bias
  gemm_bt<0><<<256, 256, 0, stream>>>(qb, wqT, bq, Qhp, MM, DMOD, DMOD);
  gemm_bt<0><<<256, 256, 0, stream>>>(kb, wkT, bk, Khp, MM, DMOD, DMOD);
  gemm_bt<0><<<256, 256, 0, stream>>>(vb, wvT, bvv, Vhp, MM, DMOD, DMOD);
  // 4) V head-transpose for PV B-operand (writes over qb — dead by now)
  vtrans<<<dim3(32, 32), 256, 0, stream>>>(Vhp, VhTp);
  // 5) fused attention: writes attn (fp32, d_out tail) + ctx (bf16, over kb)
  attn_fused<<<512, 256, 0, stream>>>(Qhp, Khp, VhTp, mask, attnp, ctxp);
  // 6) output projection into d_out head
  gemm_bt<1><<<256, 256, 0, stream>>>(ctxp, woT, bo, d_out, MM, DMOD, DMOD);
}